// Round 1
// baseline (647.414 us; speedup 1.0000x reference)
//
#include <hip/hip_runtime.h>

// Problem constants
#define B_    8
#define C_    128
#define H_    128
#define W_    128
#define KP    8     // patch size
#define SP    4     // stride
#define NH    31    // (128-8)/4+1
#define NPB   (NH*NH)       // 961 patches per batch
#define NPAT  (B_*NPB)      // 7688
#define TOK   64            // 8*8 tokens per patch

typedef float v4f  __attribute__((ext_vector_type(4)));
typedef short v8s  __attribute__((ext_vector_type(8)));

__device__ __forceinline__ unsigned short f2bf(float f) {
    unsigned int u = __builtin_bit_cast(unsigned int, f);
    u += 0x7FFFu + ((u >> 16) & 1u);   // round-to-nearest-even
    return (unsigned short)(u >> 16);
}

// LDS layout (bytes):
//   U   @ 0      size 34816 : phase1: sQ[64][136]bf16 (17408) + sK[64][136]bf16 (17408)
//                             phase2: sVT[128][72]bf16 (18432)
//                             epilog: sZ[64][129]f32   (33024)
//   sS  @ 34816  size 16640 : scores f32 [64][65]
//   sP  @ 51456  size  9216 : attn   bf16 [64][72]
//   sR1 @ 60672  size  2048 : rowmax partials f32 [64][8]
//   sR2 @ 62720  size  2048 : rowsum partials f32 [64][8]
//   sInv@ 64768  size   256 : 1/rowsum f32 [64]
// total 65024 B -> 2 blocks/CU (LDS 160 KiB)

__global__ __launch_bounds__(512, 4)
void patch_attn_kernel(const float* __restrict__ q,
                       const float* __restrict__ k,
                       const float* __restrict__ v,
                       float* __restrict__ out)
{
    __shared__ __align__(16) unsigned char lds[65024];
    unsigned short* sQ  = (unsigned short*)(lds);           // [64][136]
    unsigned short* sK  = (unsigned short*)(lds + 17408);   // [64][136]
    unsigned short* sVT = (unsigned short*)(lds);           // [128][72]
    float*          sZ  = (float*)(lds);                    // [64][129]
    float*          sS  = (float*)(lds + 34816);            // [64][65]
    unsigned short* sP  = (unsigned short*)(lds + 51456);   // [64][72]
    float*          sR1 = (float*)(lds + 60672);            // [64][8]
    float*          sR2 = (float*)(lds + 62720);            // [64][8]
    float*          sInv= (float*)(lds + 64768);            // [64]

    const int tid  = threadIdx.x;
    const int lane = tid & 63;

    const int p   = blockIdx.x;
    const int b   = p / NPB;
    const int rem = p - b * NPB;
    const int ph  = rem / NH;
    const int pw  = rem - ph * NH;
    const int h0  = ph * SP, w0 = pw * SP;

    const long baseB = (long)b * (C_ * H_ * W_);

    // ---- stage: global loads (float4 along w), Q/K -> LDS, V held in regs ----
    float4 rq[4], rk[4], rv[4];
    int cA[4], tA[4];
    #pragma unroll
    for (int g = 0; g < 4; ++g) {
        int flat4 = tid + g * 512;          // 0..2047  (2048 float4 / tensor)
        int jj = flat4 & 1;                 // which float4 within the 8-wide row
        int i  = (flat4 >> 1) & 7;          // patch row
        int c  = flat4 >> 4;                // channel
        long off = baseB + (long)c * (H_ * W_) + (long)(h0 + i) * W_ + (w0 + jj * 4);
        rq[g] = *(const float4*)(q + off);
        rk[g] = *(const float4*)(k + off);
        rv[g] = *(const float4*)(v + off);
        cA[g] = c;
        tA[g] = i * 8 + jj * 4;             // token index of element 0
    }
    #pragma unroll
    for (int g = 0; g < 4; ++g) {
        const float* fq = (const float*)&rq[g];
        const float* fk = (const float*)&rk[g];
        #pragma unroll
        for (int d = 0; d < 4; ++d) {
            sQ[(tA[g] + d) * 136 + cA[g]] = f2bf(fq[d]);
            sK[(tA[g] + d) * 136 + cA[g]] = f2bf(fk[d]);
        }
    }
    __syncthreads();   // B1: Q,K staged

    // ---- phase 1: S = Q * K^T  (16x16x32 bf16 MFMA) ----
    const float scale = 0.08838834764831845f;   // 128^-0.5
    const int wid  = tid >> 6;
    const int l15  = lane & 15;
    const int quad = lane >> 4;
    const int kb   = quad * 8;

    #pragma unroll
    for (int ti = 0; ti < 2; ++ti) {
        int tile = wid + ti * 8;            // 0..15
        int mt = tile >> 2, nt = tile & 3;
        v4f acc = {0.f, 0.f, 0.f, 0.f};
        int rowA = mt * 16 + l15;
        int rowB = nt * 16 + l15;
        #pragma unroll
        for (int kk = 0; kk < 4; ++kk) {
            v8s a  = *(const v8s*)(&sQ[rowA * 136 + kk * 32 + kb]);
            v8s bb = *(const v8s*)(&sK[rowB * 136 + kk * 32 + kb]);
            acc = __builtin_amdgcn_mfma_f32_16x16x32_bf16(a, bb, acc, 0, 0, 0);
        }
        int col   = nt * 16 + l15;
        int rbase = mt * 16 + quad * 4;
        #pragma unroll
        for (int r = 0; r < 4; ++r)
            sS[(rbase + r) * 65 + col] = acc[r] * scale;
    }
    __syncthreads();   // B2: scores ready; sQ/sK dead

    // ---- stage V -> sVT[c][s] (overlaps sQ/sK region) ----
    #pragma unroll
    for (int g = 0; g < 4; ++g) {
        const float* fv = (const float*)&rv[g];
        unsigned short tmp[4];
        #pragma unroll
        for (int d = 0; d < 4; ++d) tmp[d] = f2bf(fv[d]);
        // 8-byte contiguous write: sVT row c, s = tA..tA+3
        *(uint2*)(&sVT[cA[g] * 72 + tA[g]]) = *(const uint2*)tmp;
    }

    // ---- softmax over s (8 threads per row) ----
    const int t8 = tid >> 3;   // row 0..63
    const int sq = tid & 7;    // col-octet
    float mx = -1e30f;
    #pragma unroll
    for (int s2 = 0; s2 < 8; ++s2)
        mx = fmaxf(mx, sS[t8 * 65 + sq * 8 + s2]);
    sR1[t8 * 8 + sq] = mx;
    __syncthreads();   // B3: V staged + partial maxes
    float M = sR1[t8 * 8];
    #pragma unroll
    for (int j = 1; j < 8; ++j) M = fmaxf(M, sR1[t8 * 8 + j]);
    float psum = 0.f;
    #pragma unroll
    for (int s2 = 0; s2 < 8; ++s2) {
        float e = __expf(sS[t8 * 65 + sq * 8 + s2] - M);
        psum += e;
        sP[t8 * 72 + sq * 8 + s2] = f2bf(e);
    }
    sR2[t8 * 8 + sq] = psum;
    __syncthreads();   // B4
    if (sq == 0) {
        float L = 0.f;
        #pragma unroll
        for (int j = 0; j < 8; ++j) L += sR2[t8 * 8 + j];
        sInv[t8] = 1.0f / L;
    }
    __syncthreads();   // B5: sP, sVT, sInv all visible

    // ---- phase 2: Z = P * V  (wave wid owns c-tile wid, all 4 t-tiles) ----
    v4f zacc[4];
    #pragma unroll
    for (int mt = 0; mt < 4; ++mt) zacc[mt] = (v4f){0.f, 0.f, 0.f, 0.f};
    const int colc = wid * 16 + l15;       // channel column
    #pragma unroll
    for (int kk = 0; kk < 2; ++kk) {
        v8s bfrag = *(const v8s*)(&sVT[colc * 72 + kk * 32 + kb]);
        #pragma unroll
        for (int mt = 0; mt < 4; ++mt) {
            v8s afrag = *(const v8s*)(&sP[(mt * 16 + l15) * 72 + kk * 32 + kb]);
            zacc[mt] = __builtin_amdgcn_mfma_f32_16x16x32_bf16(afrag, bfrag, zacc[mt], 0, 0, 0);
        }
    }
    __syncthreads();   // B6: sVT reads done -> may overwrite U with sZ

    #pragma unroll
    for (int mt = 0; mt < 4; ++mt) {
        int rbase = mt * 16 + quad * 4;
        #pragma unroll
        for (int r = 0; r < 4; ++r)
            sZ[(rbase + r) * 129 + colc] = zacc[mt][r] * sInv[rbase + r];
    }
    __syncthreads();   // B7: Z staged

    // ---- scatter-add into output (j-contiguous lanes) ----
    #pragma unroll
    for (int g = 0; g < 16; ++g) {
        int flat = tid + g * 512;          // 0..8191
        int t = flat & 63;
        int c = flat >> 6;
        float val = sZ[t * 129 + c];
        long off = baseB + (long)c * (H_ * W_) + (long)(h0 + (t >> 3)) * W_ + (w0 + (t & 7));
        unsafeAtomicAdd(out + off, val);
    }
}

extern "C" void kernel_launch(void* const* d_in, const int* in_sizes, int n_in,
                              void* d_out, int out_size, void* d_ws, size_t ws_size,
                              hipStream_t stream) {
    const float* q = (const float*)d_in[0];
    const float* k = (const float*)d_in[1];
    const float* v = (const float*)d_in[2];
    float* out = (float*)d_out;

    hipMemsetAsync(out, 0, (size_t)out_size * sizeof(float), stream);
    patch_attn_kernel<<<NPAT, 512, 0, stream>>>(q, k, v, out);
}

// Round 2
// 623.040 us; speedup vs baseline: 1.0391x; 1.0391x over previous
//
#include <hip/hip_runtime.h>

// Problem constants
#define B_    8
#define C_    128
#define H_    128
#define W_    128
#define NH    31              // (128-8)/4+1
#define NPB   (NH*NH)         // 961 patches per batch (== NPAT/8, one batch per XCD)
#define NPAT  (B_*NPB)        // 7688
#define HW_   (H_*W_)
#define CHW_  (C_*HW_)

typedef float v4f __attribute__((ext_vector_type(4)));
typedef short v8s __attribute__((ext_vector_type(8)));

__device__ __forceinline__ unsigned short f2bf(float f) {
    unsigned int u = __builtin_bit_cast(unsigned int, f);
    u += 0x7FFFu + ((u >> 16) & 1u);   // RNE
    return (unsigned short)(u >> 16);
}

// LDS map (43264 B -> 3 blocks/CU):
//  sQ  @ 0      16384 : bf16 [64 t][128 c], row 256B, granule(8 u16) swizzle g^=(t&15)
//  sK  @ 16384  16384 : bf16 [64 s][128 c], same swizzle
//  sVT @ 0      16384 : bf16 [128 c][64 s], row 128B, g^=(c&7)   (reuses sQ after B2)
//  sP  @ 32768   8192 : bf16 [64 t][64 s],  row 128B, g^=(t&7)
//  sRedM @40960  1024 : f32 [4 nt][64 t] partial row-max
//  sRedL @41984  1024 : f32 [4 nt][64 t] partial row-sumexp
//  sInv  @43008   256 : f32 [64 t] 1/rowsum

__global__ __launch_bounds__(512, 6)
void patch_attn_kernel(const float* __restrict__ q,
                       const float* __restrict__ k,
                       const float* __restrict__ v,
                       float* __restrict__ out)
{
    __shared__ __align__(16) unsigned char lds[43264];
    unsigned short* sQ   = (unsigned short*)(lds);
    unsigned short* sK   = (unsigned short*)(lds + 16384);
    unsigned short* sVT  = (unsigned short*)(lds);
    unsigned short* sP   = (unsigned short*)(lds + 32768);
    float*          sRedM= (float*)(lds + 40960);
    float*          sRedL= (float*)(lds + 41984);
    float*          sInv = (float*)(lds + 43008);

    const int tid  = threadIdx.x;
    const int lane = tid & 63;
    const int wid  = tid >> 6;
    const int l15  = lane & 15;
    const int quad = lane >> 4;

    // batch-per-XCD swizzle: XCD x processes batch x's patches contiguously
    const int p   = (blockIdx.x & 7) * NPB + (blockIdx.x >> 3);
    const int b   = p / NPB;
    const int rem = p - b * NPB;
    const int ph  = rem / NH;
    const int pw  = rem - ph * NH;
    const int h0  = ph * 4, w0 = pw * 4;

    const int baseB = b * CHW_;

    // ---- global loads: 4 float4 per tensor per thread, w-contiguous ----
    float4 rq[4], rk[4], rv[4];
    int cA[4], tA[4];
    #pragma unroll
    for (int g = 0; g < 4; ++g) {
        int flat4 = tid + g * 512;          // 0..2047
        int jj = flat4 & 1;
        int i  = (flat4 >> 1) & 7;
        int c  = flat4 >> 4;
        int off = baseB + c * HW_ + (h0 + i) * W_ + (w0 + jj * 4);
        rq[g] = *(const float4*)(q + off);
        rk[g] = *(const float4*)(k + off);
        rv[g] = *(const float4*)(v + off);
        cA[g] = c;
        tA[g] = i * 8 + jj * 4;
    }
    // stage Q,K -> LDS (t-major, swizzled granules)
    #pragma unroll
    for (int g = 0; g < 4; ++g) {
        const float* fq = (const float*)&rq[g];
        const float* fk = (const float*)&rk[g];
        int c = cA[g];
        #pragma unroll
        for (int d = 0; d < 4; ++d) {
            int t = tA[g] + d;
            int idx = t * 128 + ((((c >> 3) ^ (t & 15)) << 3) | (c & 7));
            sQ[idx] = f2bf(fq[d]);
            sK[idx] = f2bf(fk[d]);
        }
    }
    __syncthreads();   // B1: Q,K staged

    // ---- phase 1: S = Q K^T, scores stay in registers ----
    const float scale = 0.08838834764831845f;
    const int nt  = wid & 3;       // this wave's s-column tile
    const int mt0 = wid >> 2;      // first t-row tile (and mt0+2)

    v4f accT[2];
    #pragma unroll
    for (int ti = 0; ti < 2; ++ti) {
        int mt = mt0 + ti * 2;
        v4f acc = {0.f, 0.f, 0.f, 0.f};
        int rowA = mt * 16 + l15;       // t
        int rowB = nt * 16 + l15;       // s
        #pragma unroll
        for (int kk = 0; kk < 4; ++kk) {
            int gph = (kk * 4 + quad) ^ l15;   // swizzled granule (row&15 == l15)
            v8s a  = *(const v8s*)(&sQ[rowA * 128 + gph * 8]);
            v8s bb = *(const v8s*)(&sK[rowB * 128 + gph * 8]);
            acc = __builtin_amdgcn_mfma_f32_16x16x32_bf16(a, bb, acc, 0, 0, 0);
        }
        #pragma unroll
        for (int r = 0; r < 4; ++r) acc[r] *= scale;
        accT[ti] = acc;
    }

    // in-register row max + sumexp over this tile's 16 columns (lanes of my quad)
    float4 mloc[2], eV[2];
    #pragma unroll
    for (int ti = 0; ti < 2; ++ti) {
        float4 m;
        #pragma unroll
        for (int r = 0; r < 4; ++r) m[r] = accT[ti][r];
        #pragma unroll
        for (int mask = 1; mask <= 8; mask <<= 1)
            #pragma unroll
            for (int r = 0; r < 4; ++r) m[r] = fmaxf(m[r], __shfl_xor(m[r], mask));
        float4 e, l;
        #pragma unroll
        for (int r = 0; r < 4; ++r) { e[r] = __expf(accT[ti][r] - m[r]); l[r] = e[r]; }
        #pragma unroll
        for (int mask = 1; mask <= 8; mask <<= 1)
            #pragma unroll
            for (int r = 0; r < 4; ++r) l[r] += __shfl_xor(l[r], mask);
        mloc[ti] = m; eV[ti] = e;
        if (l15 == 0) {
            int tb = (mt0 + ti * 2) * 16 + quad * 4;
            #pragma unroll
            for (int r = 0; r < 4; ++r) {
                sRedM[nt * 64 + tb + r] = m[r];
                sRedL[nt * 64 + tb + r] = l[r];
            }
        }
    }
    __syncthreads();   // B2: partials ready, phase-1 LDS reads done

    // ---- stage V -> sVT[c][s] (overwrites sQ region) ----
    #pragma unroll
    for (int g = 0; g < 4; ++g) {
        const float* fv = (const float*)&rv[g];
        unsigned short tmp[4];
        #pragma unroll
        for (int d = 0; d < 4; ++d) tmp[d] = f2bf(fv[d]);
        int c = cA[g], s0 = tA[g];
        int idx = c * 64 + ((((s0 >> 3) ^ (c & 7)) << 3) | (s0 & 7));
        *(uint2*)(&sVT[idx]) = *(const uint2*)tmp;
    }

    // ---- finish softmax: global M,L per row; write P (bf16) and 1/L ----
    #pragma unroll
    for (int ti = 0; ti < 2; ++ti) {
        int tb = (mt0 + ti * 2) * 16 + quad * 4;
        float4 Mv[4], Lv[4];
        #pragma unroll
        for (int n2 = 0; n2 < 4; ++n2) {
            Mv[n2] = *(const float4*)(&sRedM[n2 * 64 + tb]);
            Lv[n2] = *(const float4*)(&sRedL[n2 * 64 + tb]);
        }
        float4 M = Mv[0], L;
        #pragma unroll
        for (int n2 = 1; n2 < 4; ++n2)
            #pragma unroll
            for (int r = 0; r < 4; ++r) M[r] = fmaxf(M[r], Mv[n2][r]);
        #pragma unroll
        for (int r = 0; r < 4; ++r) L[r] = 0.f;
        #pragma unroll
        for (int n2 = 0; n2 < 4; ++n2)
            #pragma unroll
            for (int r = 0; r < 4; ++r) L[r] += Lv[n2][r] * __expf(Mv[n2][r] - M[r]);
        // P elements for my 16 columns
        #pragma unroll
        for (int r = 0; r < 4; ++r) {
            float pv = eV[ti][r] * __expf(mloc[ti][r] - M[r]);
            int t = tb + r;
            int s = nt * 16 + l15;
            sP[t * 64 + ((((s >> 3) ^ (t & 7)) << 3) | (s & 7))] = f2bf(pv);
        }
        if (nt == 0 && l15 == 0) {
            #pragma unroll
            for (int r = 0; r < 4; ++r) sInv[tb + r] = 1.0f / L[r];
        }
    }
    __syncthreads();   // B3: sVT, sP, sInv ready

    // ---- phase 2: Z^T = V^T * P^T  (wave wid owns c-tile wid, all 4 t-tiles) ----
    v4f z[4];
    #pragma unroll
    for (int n2 = 0; n2 < 4; ++n2) z[n2] = (v4f){0.f, 0.f, 0.f, 0.f};
    const int crow = wid * 16 + l15;       // c (A-operand row)
    #pragma unroll
    for (int kk = 0; kk < 2; ++kk) {
        int gph = (kk * 4 + quad) ^ (l15 & 7);   // same swizzle for sVT(^c&7) and sP(^t&7)
        v8s a = *(const v8s*)(&sVT[crow * 64 + gph * 8]);
        #pragma unroll
        for (int n2 = 0; n2 < 4; ++n2) {
            int trow = n2 * 16 + l15;
            v8s bb = *(const v8s*)(&sP[trow * 64 + gph * 8]);
            z[n2] = __builtin_amdgcn_mfma_f32_16x16x32_bf16(a, bb, z[n2], 0, 0, 0);
        }
    }

    // ---- epilogue: lanes are token-contiguous -> direct atomic scatter ----
    #pragma unroll
    for (int n2 = 0; n2 < 4; ++n2) {
        int t = n2 * 16 + l15;
        float inv = sInv[t];
        int base2 = baseB + (h0 + (t >> 3)) * W_ + (w0 + (t & 7));
        #pragma unroll
        for (int r = 0; r < 4; ++r) {
            int c = wid * 16 + quad * 4 + r;
            unsafeAtomicAdd(out + base2 + c * HW_, z[n2][r] * inv);
        }
    }
}

extern "C" void kernel_launch(void* const* d_in, const int* in_sizes, int n_in,
                              void* d_out, int out_size, void* d_ws, size_t ws_size,
                              hipStream_t stream) {
    const float* q = (const float*)d_in[0];
    const float* k = (const float*)d_in[1];
    const float* v = (const float*)d_in[2];
    float* out = (float*)d_out;

    hipMemsetAsync(out, 0, (size_t)out_size * sizeof(float), stream);
    patch_attn_kernel<<<NPAT, 512, 0, stream>>>(q, k, v, out);
}

// Round 3
// 356.632 us; speedup vs baseline: 1.8154x; 1.7470x over previous
//
#include <hip/hip_runtime.h>

// Problem constants
#define B_    8
#define C_    128
#define H_    128
#define W_    128
#define NH    31              // (128-8)/4+1
#define NPB   (NH*NH)         // 961 patches per batch
#define NPAT  (B_*NPB)        // 7688
#define HW_   (H_*W_)
#define CHW_  (C_*HW_)
#define WS_BYTES ((size_t)NPAT * 8192 * 2)   // bf16 z per patch: 125,960,192 B

typedef float v4f __attribute__((ext_vector_type(4)));
typedef short v8s __attribute__((ext_vector_type(8)));

__device__ __forceinline__ unsigned short f2bf(float f) {
    unsigned int u = __builtin_bit_cast(unsigned int, f);
    u += 0x7FFFu + ((u >> 16) & 1u);   // RNE
    return (unsigned short)(u >> 16);
}
__device__ __forceinline__ float bflo(unsigned int d) {
    return __builtin_bit_cast(float, d << 16);
}
__device__ __forceinline__ float bfhi(unsigned int d) {
    return __builtin_bit_cast(float, d & 0xFFFF0000u);
}

// ============================= PASS 1 =====================================
// Per-patch attention; z written (normalized, bf16) to ws[p][c][t], coalesced.
// LDS 43264 B -> 3 blocks/CU. Repack buffer [128][70] u16 overlays sQ/sVT
// region after phase-2 reads complete.

__global__ __launch_bounds__(512, 6)
void patch_attn_ws(const float* __restrict__ q,
                   const float* __restrict__ k,
                   const float* __restrict__ v,
                   unsigned short* __restrict__ ws)
{
    __shared__ __align__(16) unsigned char lds[43264];
    unsigned short* sQ   = (unsigned short*)(lds);
    unsigned short* sK   = (unsigned short*)(lds + 16384);
    unsigned short* sVT  = (unsigned short*)(lds);
    unsigned short* sP   = (unsigned short*)(lds + 32768);
    float*          sRedM= (float*)(lds + 40960);
    float*          sRedL= (float*)(lds + 41984);
    float*          sInv = (float*)(lds + 43008);
    unsigned short* sRep = (unsigned short*)(lds);          // [128][70] after B4

    const int tid  = threadIdx.x;
    const int lane = tid & 63;
    const int wid  = tid >> 6;
    const int l15  = lane & 15;
    const int quad = lane >> 4;

    // batch-per-XCD swizzle
    const int p   = (blockIdx.x & 7) * NPB + (blockIdx.x >> 3);
    const int b   = p / NPB;
    const int rem = p - b * NPB;
    const int ph  = rem / NH;
    const int pw  = rem - ph * NH;
    const int h0  = ph * 4, w0 = pw * 4;
    const int baseB = b * CHW_;

    // ---- global loads ----
    float4 rq[4], rk[4], rv[4];
    int cA[4], tA[4];
    #pragma unroll
    for (int g = 0; g < 4; ++g) {
        int flat4 = tid + g * 512;
        int jj = flat4 & 1;
        int i  = (flat4 >> 1) & 7;
        int c  = flat4 >> 4;
        int off = baseB + c * HW_ + (h0 + i) * W_ + (w0 + jj * 4);
        rq[g] = *(const float4*)(q + off);
        rk[g] = *(const float4*)(k + off);
        rv[g] = *(const float4*)(v + off);
        cA[g] = c;
        tA[g] = i * 8 + jj * 4;
    }
    #pragma unroll
    for (int g = 0; g < 4; ++g) {
        const float* fq = (const float*)&rq[g];
        const float* fk = (const float*)&rk[g];
        int c = cA[g];
        #pragma unroll
        for (int d = 0; d < 4; ++d) {
            int t = tA[g] + d;
            int idx = t * 128 + ((((c >> 3) ^ (t & 15)) << 3) | (c & 7));
            sQ[idx] = f2bf(fq[d]);
            sK[idx] = f2bf(fk[d]);
        }
    }
    __syncthreads();   // B1

    // ---- phase 1: S = Q K^T ----
    const float scale = 0.08838834764831845f;
    const int nt  = wid & 3;
    const int mt0 = wid >> 2;

    v4f accT[2];
    #pragma unroll
    for (int ti = 0; ti < 2; ++ti) {
        int mt = mt0 + ti * 2;
        v4f acc = {0.f, 0.f, 0.f, 0.f};
        int rowA = mt * 16 + l15;
        int rowB = nt * 16 + l15;
        #pragma unroll
        for (int kk = 0; kk < 4; ++kk) {
            int gph = (kk * 4 + quad) ^ l15;
            v8s a  = *(const v8s*)(&sQ[rowA * 128 + gph * 8]);
            v8s bb = *(const v8s*)(&sK[rowB * 128 + gph * 8]);
            acc = __builtin_amdgcn_mfma_f32_16x16x32_bf16(a, bb, acc, 0, 0, 0);
        }
        #pragma unroll
        for (int r = 0; r < 4; ++r) acc[r] *= scale;
        accT[ti] = acc;
    }

    // in-register partial softmax over 16 columns
    float4 mloc[2], eV[2];
    #pragma unroll
    for (int ti = 0; ti < 2; ++ti) {
        float4 m;
        #pragma unroll
        for (int r = 0; r < 4; ++r) m[r] = accT[ti][r];
        #pragma unroll
        for (int mask = 1; mask <= 8; mask <<= 1)
            #pragma unroll
            for (int r = 0; r < 4; ++r) m[r] = fmaxf(m[r], __shfl_xor(m[r], mask));
        float4 e, l;
        #pragma unroll
        for (int r = 0; r < 4; ++r) { e[r] = __expf(accT[ti][r] - m[r]); l[r] = e[r]; }
        #pragma unroll
        for (int mask = 1; mask <= 8; mask <<= 1)
            #pragma unroll
            for (int r = 0; r < 4; ++r) l[r] += __shfl_xor(l[r], mask);
        mloc[ti] = m; eV[ti] = e;
        if (l15 == 0) {
            int tb = (mt0 + ti * 2) * 16 + quad * 4;
            #pragma unroll
            for (int r = 0; r < 4; ++r) {
                sRedM[nt * 64 + tb + r] = m[r];
                sRedL[nt * 64 + tb + r] = l[r];
            }
        }
    }
    __syncthreads();   // B2

    // ---- stage V -> sVT[c][s] ----
    #pragma unroll
    for (int g = 0; g < 4; ++g) {
        const float* fv = (const float*)&rv[g];
        unsigned short tmp[4];
        #pragma unroll
        for (int d = 0; d < 4; ++d) tmp[d] = f2bf(fv[d]);
        int c = cA[g], s0 = tA[g];
        int idx = c * 64 + ((((s0 >> 3) ^ (c & 7)) << 3) | (s0 & 7));
        *(uint2*)(&sVT[idx]) = *(const uint2*)tmp;
    }

    // ---- finish softmax ----
    #pragma unroll
    for (int ti = 0; ti < 2; ++ti) {
        int tb = (mt0 + ti * 2) * 16 + quad * 4;
        float4 Mv[4], Lv[4];
        #pragma unroll
        for (int n2 = 0; n2 < 4; ++n2) {
            Mv[n2] = *(const float4*)(&sRedM[n2 * 64 + tb]);
            Lv[n2] = *(const float4*)(&sRedL[n2 * 64 + tb]);
        }
        float4 M = Mv[0], L;
        #pragma unroll
        for (int n2 = 1; n2 < 4; ++n2)
            #pragma unroll
            for (int r = 0; r < 4; ++r) M[r] = fmaxf(M[r], Mv[n2][r]);
        #pragma unroll
        for (int r = 0; r < 4; ++r) L[r] = 0.f;
        #pragma unroll
        for (int n2 = 0; n2 < 4; ++n2)
            #pragma unroll
            for (int r = 0; r < 4; ++r) L[r] += Lv[n2][r] * __expf(Mv[n2][r] - M[r]);
        #pragma unroll
        for (int r = 0; r < 4; ++r) {
            float pv = eV[ti][r] * __expf(mloc[ti][r] - M[r]);
            int t = tb + r;
            int s = nt * 16 + l15;
            sP[t * 64 + ((((s >> 3) ^ (t & 7)) << 3) | (s & 7))] = f2bf(pv);
        }
        if (nt == 0 && l15 == 0) {
            #pragma unroll
            for (int r = 0; r < 4; ++r) sInv[tb + r] = 1.0f / L[r];
        }
    }
    __syncthreads();   // B3

    // ---- phase 2: Z^T = V^T * P^T ----
    v4f z[4];
    #pragma unroll
    for (int n2 = 0; n2 < 4; ++n2) z[n2] = (v4f){0.f, 0.f, 0.f, 0.f};
    const int crow = wid * 16 + l15;
    #pragma unroll
    for (int kk = 0; kk < 2; ++kk) {
        int gph = (kk * 4 + quad) ^ (l15 & 7);
        v8s a = *(const v8s*)(&sVT[crow * 64 + gph * 8]);
        #pragma unroll
        for (int n2 = 0; n2 < 4; ++n2) {
            int trow = n2 * 16 + l15;
            v8s bb = *(const v8s*)(&sP[trow * 64 + gph * 8]);
            z[n2] = __builtin_amdgcn_mfma_f32_16x16x32_bf16(a, bb, z[n2], 0, 0, 0);
        }
    }
    __syncthreads();   // B4: phase-2 LDS reads done; sQ/sVT region reusable

    // ---- epilogue: repack via LDS, coalesced bf16 store to ws[p][c][t] ----
    #pragma unroll
    for (int n2 = 0; n2 < 4; ++n2) {
        int t = n2 * 16 + l15;
        float inv = sInv[t];
        #pragma unroll
        for (int r = 0; r < 4; ++r) {
            int c = wid * 16 + quad * 4 + r;
            sRep[c * 70 + t] = f2bf(z[n2][r] * inv);
        }
    }
    __syncthreads();   // B5
    {
        int c = tid >> 2, tseg = tid & 3;
        const unsigned short* src = &sRep[c * 70 + tseg * 16];
        uint2 d0 = *(const uint2*)(src);
        uint2 d1 = *(const uint2*)(src + 4);
        uint2 d2 = *(const uint2*)(src + 8);
        uint2 d3 = *(const uint2*)(src + 12);
        unsigned short* dst = ws + (size_t)p * 8192 + c * 64 + tseg * 16;
        uint4 w0v; w0v.x = d0.x; w0v.y = d0.y; w0v.z = d1.x; w0v.w = d1.y;
        uint4 w1v; w1v.x = d2.x; w1v.y = d2.y; w1v.z = d3.x; w1v.w = d3.y;
        ((uint4*)dst)[0] = w0v;
        ((uint4*)dst)[1] = w1v;
    }
}

// ============================= PASS 2 =====================================
// Gather-merge: out(b,c,h,w) = sum of <=4 ws contributions. Full-line reads,
// neighbor halves via shfl, coalesced float4 stores. No atomics, no memset.

__global__ __launch_bounds__(256, 8)
void merge_kernel(const unsigned short* __restrict__ ws,
                  float* __restrict__ out)
{
    const int tid  = threadIdx.x;
    const int lane = tid & 63;
    const int l    = tid & 31;      // w-quad: w = 4l..4l+3
    const int csub = tid >> 5;      // 0..7
    const int b    = blockIdx.x & 7;          // batch-per-XCD
    const int rest = blockIdx.x >> 3;         // 0..511
    const int hq   = rest >> 4;               // 0..31 : h = 4hq + hr
    const int cg   = rest & 15;
    const int c    = cg * 8 + csub;

    uint4 A[4]  = {};   // patch (hq, l):   line0 = th 0..3, tw 0..7
    uint4 Bv[4] = {};   // patch (hq-1, l): line1 = th 4..7, tw 0..7
    if (hq <= 30 && l <= 30) {
        const unsigned short* p1 = ws + ((size_t)(b * NPB + hq * NH + l) * 128 + c) * 64;
        #pragma unroll
        for (int hr = 0; hr < 4; ++hr) A[hr] = *(const uint4*)(p1 + hr * 8);
    }
    if (hq >= 1 && l <= 30) {
        const unsigned short* p0 = ws + ((size_t)(b * NPB + (hq - 1) * NH + l) * 128 + c) * 64 + 32;
        #pragma unroll
        for (int hr = 0; hr < 4; ++hr) Bv[hr] = *(const uint4*)(p0 + hr * 8);
    }

    const int src = (lane == 0) ? 0 : (lane - 1);   // prev lane within wave
    float4 o[4];
    #pragma unroll
    for (int hr = 0; hr < 4; ++hr) {
        unsigned int az = (unsigned int)__shfl((int)A[hr].z,  src);
        unsigned int aw = (unsigned int)__shfl((int)A[hr].w,  src);
        unsigned int bz = (unsigned int)__shfl((int)Bv[hr].z, src);
        unsigned int bw = (unsigned int)__shfl((int)Bv[hr].w, src);
        if (l == 0) { az = 0u; aw = 0u; bz = 0u; bw = 0u; }
        float4 r;
        r.x = bflo(A[hr].x) + bflo(Bv[hr].x) + bflo(az) + bflo(bz);
        r.y = bfhi(A[hr].x) + bfhi(Bv[hr].x) + bfhi(az) + bfhi(bz);
        r.z = bflo(A[hr].y) + bflo(Bv[hr].y) + bflo(aw) + bflo(bw);
        r.w = bfhi(A[hr].y) + bfhi(Bv[hr].y) + bfhi(aw) + bfhi(bw);
        o[hr] = r;
    }

    float* op = out + b * CHW_ + c * HW_ + (hq * 4) * W_ + l * 4;
    #pragma unroll
    for (int hr = 0; hr < 4; ++hr)
        *(float4*)(op + hr * W_) = o[hr];
}

// ========================= FALLBACK (atomic) ==============================

__global__ __launch_bounds__(512, 6)
void patch_attn_atomic(const float* __restrict__ q,
                       const float* __restrict__ k,
                       const float* __restrict__ v,
                       float* __restrict__ out)
{
    __shared__ __align__(16) unsigned char lds[43264];
    unsigned short* sQ   = (unsigned short*)(lds);
    unsigned short* sK   = (unsigned short*)(lds + 16384);
    unsigned short* sVT  = (unsigned short*)(lds);
    unsigned short* sP   = (unsigned short*)(lds + 32768);
    float*          sRedM= (float*)(lds + 40960);
    float*          sRedL= (float*)(lds + 41984);
    float*          sInv = (float*)(lds + 43008);

    const int tid  = threadIdx.x;
    const int lane = tid & 63;
    const int wid  = tid >> 6;
    const int l15  = lane & 15;
    const int quad = lane >> 4;

    const int p   = (blockIdx.x & 7) * NPB + (blockIdx.x >> 3);
    const int b   = p / NPB;
    const int rem = p - b * NPB;
    const int ph  = rem / NH;
    const int pw  = rem - ph * NH;
    const int h0  = ph * 4, w0 = pw * 4;
    const int baseB = b * CHW_;

    float4 rq[4], rk[4], rv[4];
    int cA[4], tA[4];
    #pragma unroll
    for (int g = 0; g < 4; ++g) {
        int flat4 = tid + g * 512;
        int jj = flat4 & 1;
        int i  = (flat4 >> 1) & 7;
        int c  = flat4 >> 4;
        int off = baseB + c * HW_ + (h0 + i) * W_ + (w0 + jj * 4);
        rq[g] = *(const float4*)(q + off);
        rk[g] = *(const float4*)(k + off);
        rv[g] = *(const float4*)(v + off);
        cA[g] = c;
        tA[g] = i * 8 + jj * 4;
    }
    #pragma unroll
    for (int g = 0; g < 4; ++g) {
        const float* fq = (const float*)&rq[g];
        const float* fk = (const float*)&rk[g];
        int c = cA[g];
        #pragma unroll
        for (int d = 0; d < 4; ++d) {
            int t = tA[g] + d;
            int idx = t * 128 + ((((c >> 3) ^ (t & 15)) << 3) | (c & 7));
            sQ[idx] = f2bf(fq[d]);
            sK[idx] = f2bf(fk[d]);
        }
    }
    __syncthreads();

    const float scale = 0.08838834764831845f;
    const int nt  = wid & 3;
    const int mt0 = wid >> 2;

    v4f accT[2];
    #pragma unroll
    for (int ti = 0; ti < 2; ++ti) {
        int mt = mt0 + ti * 2;
        v4f acc = {0.f, 0.f, 0.f, 0.f};
        int rowA = mt * 16 + l15;
        int rowB = nt * 16 + l15;
        #pragma unroll
        for (int kk = 0; kk < 4; ++kk) {
            int gph = (kk * 4 + quad) ^ l15;
            v8s a  = *(const v8s*)(&sQ[rowA * 128 + gph * 8]);
            v8s bb = *(const v8s*)(&sK[rowB * 128 + gph * 8]);
            acc = __builtin_amdgcn_mfma_f32_16x16x32_bf16(a, bb, acc, 0, 0, 0);
        }
        #pragma unroll
        for (int r = 0; r < 4; ++r) acc[r] *= scale;
        accT[ti] = acc;
    }

    float4 mloc[2], eV[2];
    #pragma unroll
    for (int ti = 0; ti < 2; ++ti) {
        float4 m;
        #pragma unroll
        for (int r = 0; r < 4; ++r) m[r] = accT[ti][r];
        #pragma unroll
        for (int mask = 1; mask <= 8; mask <<= 1)
            #pragma unroll
            for (int r = 0; r < 4; ++r) m[r] = fmaxf(m[r], __shfl_xor(m[r], mask));
        float4 e, l;
        #pragma unroll
        for (int r = 0; r < 4; ++r) { e[r] = __expf(accT[ti][r] - m[r]); l[r] = e[r]; }
        #pragma unroll
        for (int mask = 1; mask <= 8; mask <<= 1)
            #pragma unroll
            for (int r = 0; r < 4; ++r) l[r] += __shfl_xor(l[r], mask);
        mloc[ti] = m; eV[ti] = e;
        if (l15 == 0) {
            int tb = (mt0 + ti * 2) * 16 + quad * 4;
            #pragma unroll
            for (int r = 0; r < 4; ++r) {
                sRedM[nt * 64 + tb + r] = m[r];
                sRedL[nt * 64 + tb + r] = l[r];
            }
        }
    }
    __syncthreads();

    #pragma unroll
    for (int g = 0; g < 4; ++g) {
        const float* fv = (const float*)&rv[g];
        unsigned short tmp[4];
        #pragma unroll
        for (int d = 0; d < 4; ++d) tmp[d] = f2bf(fv[d]);
        int c = cA[g], s0 = tA[g];
        int idx = c * 64 + ((((s0 >> 3) ^ (c & 7)) << 3) | (s0 & 7));
        *(uint2*)(&sVT[idx]) = *(const uint2*)tmp;
    }

    #pragma unroll
    for (int ti = 0; ti < 2; ++ti) {
        int tb = (mt0 + ti * 2) * 16 + quad * 4;
        float4 Mv[4], Lv[4];
        #pragma unroll
        for (int n2 = 0; n2 < 4; ++n2) {
            Mv[n2] = *(const float4*)(&sRedM[n2 * 64 + tb]);
            Lv[n2] = *(const float4*)(&sRedL[n2 * 64 + tb]);
        }
        float4 M = Mv[0], L;
        #pragma unroll
        for (int n2 = 1; n2 < 4; ++n2)
            #pragma unroll
            for (int r = 0; r < 4; ++r) M[r] = fmaxf(M[r], Mv[n2][r]);
        #pragma unroll
        for (int r = 0; r < 4; ++r) L[r] = 0.f;
        #pragma unroll
        for (int n2 = 0; n2 < 4; ++n2)
            #pragma unroll
            for (int r = 0; r < 4; ++r) L[r] += Lv[n2][r] * __expf(Mv[n2][r] - M[r]);
        #pragma unroll
        for (int r = 0; r < 4; ++r) {
            float pv = eV[ti][r] * __expf(mloc[ti][r] - M[r]);
            int t = tb + r;
            int s = nt * 16 + l15;
            sP[t * 64 + ((((s >> 3) ^ (t & 7)) << 3) | (s & 7))] = f2bf(pv);
        }
        if (nt == 0 && l15 == 0) {
            #pragma unroll
            for (int r = 0; r < 4; ++r) sInv[tb + r] = 1.0f / L[r];
        }
    }
    __syncthreads();

    v4f z[4];
    #pragma unroll
    for (int n2 = 0; n2 < 4; ++n2) z[n2] = (v4f){0.f, 0.f, 0.f, 0.f};
    const int crow = wid * 16 + l15;
    #pragma unroll
    for (int kk = 0; kk < 2; ++kk) {
        int gph = (kk * 4 + quad) ^ (l15 & 7);
        v8s a = *(const v8s*)(&sVT[crow * 64 + gph * 8]);
        #pragma unroll
        for (int n2 = 0; n2 < 4; ++n2) {
            int trow = n2 * 16 + l15;
            v8s bb = *(const v8s*)(&sP[trow * 64 + gph * 8]);
            z[n2] = __builtin_amdgcn_mfma_f32_16x16x32_bf16(a, bb, z[n2], 0, 0, 0);
        }
    }

    #pragma unroll
    for (int n2 = 0; n2 < 4; ++n2) {
        int t = n2 * 16 + l15;
        float inv = sInv[t];
        int base2 = baseB + (h0 + (t >> 3)) * W_ + (w0 + (t & 7));
        #pragma unroll
        for (int r = 0; r < 4; ++r) {
            int c = wid * 16 + quad * 4 + r;
            unsafeAtomicAdd(out + base2 + c * HW_, z[n2][r] * inv);
        }
    }
}

extern "C" void kernel_launch(void* const* d_in, const int* in_sizes, int n_in,
                              void* d_out, int out_size, void* d_ws, size_t ws_size,
                              hipStream_t stream) {
    const float* q = (const float*)d_in[0];
    const float* k = (const float*)d_in[1];
    const float* v = (const float*)d_in[2];
    float* out = (float*)d_out;

    if (ws_size >= WS_BYTES) {
        unsigned short* ws = (unsigned short*)d_ws;
        patch_attn_ws<<<NPAT, 512, 0, stream>>>(q, k, v, ws);
        merge_kernel<<<8 * 32 * 16, 256, 0, stream>>>(ws, out);
    } else {
        hipMemsetAsync(out, 0, (size_t)out_size * sizeof(float), stream);
        patch_attn_atomic<<<NPAT, 512, 0, stream>>>(q, k, v, out);
    }
}